// Round 1
// baseline (16724.251 us; speedup 1.0000x reference)
//
#include <hip/hip_runtime.h>

// GRU scan: T=512, B=128, H=512. fp32 throughout.
// Output layout: out[0 : B*H) = h_final, out[B*H : B*H + T*B*H) = ys.
// ys doubles as the h ping-pong storage (step t reads ys[t-1], writes ys[t]).
// Round 0: fused kernel (gi computed in-step; no workspace dependence),
// one launch per time step (512 graph nodes).

#define TT 512
#define BB 128
#define HH 512
#define H3 1536

__global__ __launch_bounds__(256) void gru_step(
    const float* __restrict__ xt,    // [B,H] slice x[t]
    const float* __restrict__ hprev, // [B,H]
    const float* __restrict__ Wi,    // [H,3H] (r|z|n)
    const float* __restrict__ bi,    // [3H]
    const float* __restrict__ Wh,    // [H,3H]
    const float* __restrict__ bhn,   // [H]
    float* __restrict__ hnew,        // [B,H]
    float* __restrict__ hfin)        // [B,H] or nullptr (written at t==T-1)
{
    // Tile: BM=8 batch rows x BN=32 h-columns per workgroup.
    // Grid: (H/32=16) x (B/8=16) = 256 workgroups -> ~1 per CU.
    constexpr int BM = 8;
    __shared__ float Xs[BM][HH];
    __shared__ float Hs[BM][HH];

    const int tid = threadIdx.x;          // 0..255
    const int b0  = blockIdx.y * BM;      // batch tile origin
    const int n0  = blockIdx.x * 32;      // column tile origin

    // Stage x_t and h_prev tiles (8 x 512 floats each) via float4, coalesced.
    for (int i = tid; i < BM * (HH / 4); i += 256) {
        const int r = i / (HH / 4);
        const int c = i % (HH / 4);
        ((float4*)&Xs[r][0])[c] = ((const float4*)(xt    + (size_t)(b0 + r) * HH))[c];
        ((float4*)&Hs[r][0])[c] = ((const float4*)(hprev + (size_t)(b0 + r) * HH))[c];
    }
    __syncthreads();

    const int j  = n0 + (tid & 31);       // h-column, 0..511
    const int bb = tid >> 5;              // 0..7 (local batch row)
    const int b  = b0 + bb;

    float ar = 0.f, az = 0.f, an = 0.f;   // x @ Wi dots (r,z,n)
    float br = 0.f, bz = 0.f, bn = 0.f;   // h @ Wh dots (r,z,n)

    const float* __restrict__ wi = Wi + j;
    const float* __restrict__ wh = Wh + j;

    // 6 coalesced global loads + 2 LDS broadcasts + 6 FMA per k.
    #pragma unroll 8
    for (int k = 0; k < HH; ++k) {
        const float xv = Xs[bb][k];
        const float hv = Hs[bb][k];
        const float* wik = wi + (size_t)k * H3;
        const float* whk = wh + (size_t)k * H3;
        ar += xv * wik[0];
        az += xv * wik[HH];
        an += xv * wik[2 * HH];
        br += hv * whk[0];
        bz += hv * whk[HH];
        bn += hv * whk[2 * HH];
    }

    const float gr = ar + br + bi[j];
    const float gz = az + bz + bi[j + HH];
    const float r  = 1.f / (1.f + __expf(-gr));
    const float z  = 1.f / (1.f + __expf(-gz));
    const float pre = an + bi[j + 2 * HH] + r * (bn + bhn[j]);
    // tanh via exp2-backed __expf; stable at both tails:
    // pre -> +inf: e2 = inf -> n = 1;  pre -> -inf: e2 = 0 -> n = -1.
    const float e2 = __expf(2.f * pre);
    const float n  = 1.f - 2.f / (e2 + 1.f);

    const float hp = Hs[bb][j];
    const float h  = (1.f - z) * n + z * hp;

    hnew[(size_t)b * HH + j] = h;
    if (hfin) hfin[(size_t)b * HH + j] = h;
}

extern "C" void kernel_launch(void* const* d_in, const int* in_sizes, int n_in,
                              void* d_out, int out_size, void* d_ws, size_t ws_size,
                              hipStream_t stream) {
    const float* x   = (const float*)d_in[0];  // [T,B,H]
    const float* h0  = (const float*)d_in[1];  // [B,H]
    const float* Wi  = (const float*)d_in[2];  // [H,3H]
    const float* bi  = (const float*)d_in[3];  // [3H]
    const float* Wh  = (const float*)d_in[4];  // [H,3H]
    const float* bhn = (const float*)d_in[5];  // [H]

    float* out  = (float*)d_out;
    float* hfin = out;                         // [B,H]
    float* ys   = out + (size_t)BB * HH;       // [T,B,H]

    const dim3 grid(HH / 32, BB / 8);          // 16 x 16 = 256 wgs
    for (int t = 0; t < TT; ++t) {
        const float* hp = (t == 0) ? h0 : (ys + (size_t)(t - 1) * BB * HH);
        float*       hn = ys + (size_t)t * BB * HH;
        gru_step<<<grid, 256, 0, stream>>>(
            x + (size_t)t * BB * HH, hp, Wi, bi, Wh, bhn, hn,
            (t == TT - 1) ? hfin : nullptr);
    }
}

// Round 2
// 13273.492 us; speedup vs baseline: 1.2600x; 1.2600x over previous
//
#include <hip/hip_runtime.h>

// GRU scan: T=512, B=128, H=512, fp32.
// out[0:B*H) = h_final, out[B*H:] = ys[T,B,H]; ys doubles as h ping-pong.
//
// v2: per-step fused kernel C3[b][j][g] = x_t@Wi + h@Wh (+gates):
//  - tile 16b x 16j per wg, grid 256 (1 wg/CU), 512 threads = 8 waves
//  - split-K: waves 0-3 = x@Wi (K-slices of 128), waves 4-7 = h@Wh
//  - weights: float4 global loads (full 64B line per wave-instr, no dup)
//  - x/h tiles in LDS (pad 516 -> 2-way bank alias = free)
//  - LDS reduction across waves + fused gate epilogue
//  - XCD swizzle: XCD k gets j-tiles {4k..4k+3} -> 786KB weight slice L2-resident

#define TT 512
#define BB 128
#define HH 512
#define H3 1536

__global__ __launch_bounds__(512, 2) void gru_step(
    const float* __restrict__ xt,    // [B,H] slice x[t]
    const float* __restrict__ hprev, // [B,H]
    const float* __restrict__ Wi,    // [H,3H] (r|z|n)
    const float* __restrict__ bi,    // [3H]
    const float* __restrict__ Wh,    // [H,3H]
    const float* __restrict__ bhn,   // [H]
    float* __restrict__ hnew,        // [B,H]
    float* __restrict__ hfin)        // [B,H] or nullptr
{
    __shared__ float Xs[16][516];
    __shared__ float Hs[16][516];
    __shared__ float red[8][16][16][3];   // [wave][b][jcol][gate]

    const int tid = threadIdx.x;
    const int n   = blockIdx.x;
    // XCD swizzle: j-tile = (n&7)*4 + ((n>>3)&3), b-tile = n>>5
    const int jt = (n & 7) * 4 + ((n >> 3) & 3);  // 0..31
    const int bt = n >> 5;                        // 0..7
    const int j0 = jt * 16;
    const int b0 = bt * 16;

    // ---- stage x_t and h_prev tiles (16 x 512 floats each), coalesced float4
    for (int idx = tid; idx < 16 * 128; idx += 512) {
        const int r = idx >> 7;      // 0..15
        const int c = idx & 127;     // float4 index 0..127
        const float4 xv = ((const float4*)(xt    + (size_t)(b0 + r) * HH))[c];
        const float4 hv = ((const float4*)(hprev + (size_t)(b0 + r) * HH))[c];
        *(float4*)&Xs[r][c * 4] = xv;
        *(float4*)&Hs[r][c * 4] = hv;
    }
    __syncthreads();

    // ---- main: each wave accumulates a K=128 slice of one matrix product
    const int w   = tid >> 6;          // 0..7
    const int mat = w >> 2;            // 0 = x@Wi, 1 = h@Wh
    const int k0  = (w & 3) * 128;
    const int b   = tid & 15;          // local batch row
    const int jg  = (tid >> 4) & 3;    // j-group (4 cols each)
    const int j   = j0 + jg * 4;

    const float* __restrict__ W    = mat ? Wh : Wi;
    const float* __restrict__ vals = mat ? &Hs[b][0] : &Xs[b][0];

    float4 ar = {0.f, 0.f, 0.f, 0.f};
    float4 az = {0.f, 0.f, 0.f, 0.f};
    float4 an = {0.f, 0.f, 0.f, 0.f};

    const float* wp = W + (size_t)k0 * H3 + j;
    #pragma unroll 4
    for (int k = 0; k < 128; ++k) {
        const float  v  = vals[k0 + k];
        const float4 wr = *(const float4*)(wp);
        const float4 wz = *(const float4*)(wp + 512);
        const float4 wn = *(const float4*)(wp + 1024);
        ar.x += v * wr.x; ar.y += v * wr.y; ar.z += v * wr.z; ar.w += v * wr.w;
        az.x += v * wz.x; az.y += v * wz.y; az.z += v * wz.z; az.w += v * wz.w;
        an.x += v * wn.x; an.y += v * wn.y; an.z += v * wn.z; an.w += v * wn.w;
        wp += H3;
    }

    // ---- write partials
    {
        float* rp = &red[w][b][jg * 4][0];   // 4 cols x 3 gates, contiguous
        rp[0] = ar.x;  rp[1] = az.x;  rp[2] = an.x;
        rp[3] = ar.y;  rp[4] = az.y;  rp[5] = an.y;
        rp[6] = ar.z;  rp[7] = az.z;  rp[8] = an.z;
        rp[9] = ar.w;  rp[10] = az.w; rp[11] = an.w;
    }
    __syncthreads();

    // ---- epilogue: 256 threads, one (b,j) each
    if (tid < 256) {
        const int eb = tid >> 4;
        const int jl = tid & 15;
        const int jj = j0 + jl;

        float gir = 0.f, giz = 0.f, gin = 0.f;
        float ghr = 0.f, ghz = 0.f, ghn = 0.f;
        #pragma unroll
        for (int ww = 0; ww < 4; ++ww) {
            gir += red[ww][eb][jl][0];
            giz += red[ww][eb][jl][1];
            gin += red[ww][eb][jl][2];
        }
        #pragma unroll
        for (int ww = 4; ww < 8; ++ww) {
            ghr += red[ww][eb][jl][0];
            ghz += red[ww][eb][jl][1];
            ghn += red[ww][eb][jl][2];
        }

        const float gr = gir + ghr + bi[jj];
        const float gz = giz + ghz + bi[jj + HH];
        const float r  = 1.f / (1.f + __expf(-gr));
        const float z  = 1.f / (1.f + __expf(-gz));
        const float pre = gin + bi[jj + 2 * HH] + r * (ghn + bhn[jj]);
        const float e2 = __expf(2.f * pre);
        const float nn = 1.f - 2.f / (e2 + 1.f);

        const float hp = Hs[eb][jj];
        const float h  = (1.f - z) * nn + z * hp;

        const size_t o = (size_t)(b0 + eb) * HH + jj;
        hnew[o] = h;
        if (hfin) hfin[o] = h;
    }
}

extern "C" void kernel_launch(void* const* d_in, const int* in_sizes, int n_in,
                              void* d_out, int out_size, void* d_ws, size_t ws_size,
                              hipStream_t stream) {
    const float* x   = (const float*)d_in[0];  // [T,B,H]
    const float* h0  = (const float*)d_in[1];  // [B,H]
    const float* Wi  = (const float*)d_in[2];  // [H,3H]
    const float* bi  = (const float*)d_in[3];  // [3H]
    const float* Wh  = (const float*)d_in[4];  // [H,3H]
    const float* bhn = (const float*)d_in[5];  // [H]

    float* out  = (float*)d_out;
    float* hfin = out;                          // [B,H]
    float* ys   = out + (size_t)BB * HH;        // [T,B,H]

    for (int t = 0; t < TT; ++t) {
        const float* hp = (t == 0) ? h0 : (ys + (size_t)(t - 1) * BB * HH);
        float*       hn = ys + (size_t)t * BB * HH;
        gru_step<<<256, 512, 0, stream>>>(
            x + (size_t)t * BB * HH, hp, Wi, bi, Wh, bhn, hn,
            (t == TT - 1) ? hfin : nullptr);
    }
}